// Round 1
// baseline (194.573 us; speedup 1.0000x reference)
//
#include <hip/hip_runtime.h>
#include <cmath>

#define B_ 4
#define S_ 4096
#define D_ 1024
#define H_ 128
#define M_ (B_*S_)   // 16384 total rows

typedef _Float16 half8 __attribute__((ext_vector_type(8)));
typedef _Float16 half4 __attribute__((ext_vector_type(4)));
typedef float f32x4 __attribute__((ext_vector_type(4)));

// ---------------------------------------------------------------------------
// Kernel 1: QKV projection.  out = x @ W^T + b  (fp32 in, fp16 out)
// grid = (M/64, 3): y=0 -> q (scaled by 1/sqrt(H)), y=1 -> k, y=2 -> v^T
// BM=64, BN=128(=H), BK=64. 256 threads = 4 waves, each wave: 16 rows x 128 cols.
// ---------------------------------------------------------------------------
__global__ __launch_bounds__(256, 3) void proj_kernel(
    const float* __restrict__ x,
    const float* __restrict__ Wq, const float* __restrict__ bq,
    const float* __restrict__ Wk, const float* __restrict__ bk,
    const float* __restrict__ Wv, const float* __restrict__ bv,
    _Float16* __restrict__ qh, _Float16* __restrict__ kh,
    _Float16* __restrict__ vt)
{
    __shared__ _Float16 Xs[64][72];    // +8 pad: row stride 144B -> conflict-free
    __shared__ _Float16 Wsh[128][72];

    const int t = threadIdx.x;
    const int yb = blockIdx.y;
    const float* __restrict__ W    = (yb == 0) ? Wq : (yb == 1) ? Wk : Wv;
    const float* __restrict__ bias = (yb == 0) ? bq : (yb == 1) ? bk : bv;
    const int m0 = blockIdx.x * 64;
    const int w = t >> 6, lane = t & 63;
    const int lg = lane >> 4, lr = lane & 15;

    f32x4 acc[8];
    #pragma unroll
    for (int i = 0; i < 8; ++i) acc[i] = f32x4{0.f, 0.f, 0.f, 0.f};

    const int xrow = t >> 2, xc = (t & 3) * 16;   // X tile: 64 rows x 64 cols
    const int wrow = t >> 1, wc = (t & 1) * 32;   // W tile: 128 rows x 64 cols

    for (int kt = 0; kt < 16; ++kt) {
        const int k0 = kt * 64;
        {
            const float* src = x + (size_t)(m0 + xrow) * D_ + k0 + xc;
            #pragma unroll
            for (int i = 0; i < 4; ++i) {
                float4 f = *(const float4*)(src + 4 * i);
                half4 h = { (_Float16)f.x, (_Float16)f.y, (_Float16)f.z, (_Float16)f.w };
                *(half4*)&Xs[xrow][xc + 4 * i] = h;
            }
        }
        {
            const float* src = W + (size_t)wrow * D_ + k0 + wc;
            #pragma unroll
            for (int i = 0; i < 8; ++i) {
                float4 f = *(const float4*)(src + 4 * i);
                half4 h = { (_Float16)f.x, (_Float16)f.y, (_Float16)f.z, (_Float16)f.w };
                *(half4*)&Wsh[wrow][wc + 4 * i] = h;
            }
        }
        __syncthreads();
        #pragma unroll
        for (int kk = 0; kk < 2; ++kk) {
            half8 a = *(const half8*)&Xs[w * 16 + lr][kk * 32 + 8 * lg];
            #pragma unroll
            for (int ni = 0; ni < 8; ++ni) {
                half8 bf = *(const half8*)&Wsh[ni * 16 + lr][kk * 32 + 8 * lg];
                acc[ni] = __builtin_amdgcn_mfma_f32_16x16x32_f16(a, bf, acc[ni], 0, 0, 0);
            }
        }
        __syncthreads();
    }

    const float qscale = 0.08838834764831845f;  // 1/sqrt(128)
    const int rowb = m0 + w * 16 + lg * 4;      // C/D: row = 4*(lane>>4)+r, col = ni*16 + (lane&15)
    #pragma unroll
    for (int ni = 0; ni < 8; ++ni) {
        const int col = ni * 16 + lr;
        const float bval = bias[col];
        if (yb == 0) {
            #pragma unroll
            for (int r = 0; r < 4; ++r)
                qh[(size_t)(rowb + r) * H_ + col] = (_Float16)((acc[ni][r] + bval) * qscale);
        } else if (yb == 1) {
            #pragma unroll
            for (int r = 0; r < 4; ++r)
                kh[(size_t)(rowb + r) * H_ + col] = (_Float16)(acc[ni][r] + bval);
        } else {
            const int bb = rowb >> 12, s0 = rowb & (S_ - 1);
            half4 h;
            #pragma unroll
            for (int r = 0; r < 4; ++r) h[r] = (_Float16)(acc[ni][r] + bval);
            *(half4*)&vt[(size_t)bb * H_ * S_ + (size_t)col * S_ + s0] = h;
        }
    }
}

// ---------------------------------------------------------------------------
// Kernel 2: flash attention with KV-split. Each block: 64 Q rows, one KV slice.
// 4 waves x 16 Q rows. KVBLK=64. Writes unnormalized O + (m,l) partials.
// ---------------------------------------------------------------------------
__global__ __launch_bounds__(256, 3) void attn_kernel(
    const _Float16* __restrict__ qh, const _Float16* __restrict__ kh,
    const _Float16* __restrict__ vt, const int* __restrict__ mask,
    float* __restrict__ pout, float* __restrict__ pm, float* __restrict__ pl,
    const int nsplit)
{
    __shared__ _Float16 Ks[64][136];      // [kv][h], +8 pad
    __shared__ _Float16 Vs[128][72];      // [h][kv], +8 pad (from v^T: contiguous)
    __shared__ _Float16 Ps[4][16][72];    // per-wave P tile
    __shared__ int ms[64];

    const int t = threadIdx.x;
    const int nblocks = 256 * nsplit;
    const int chunk = nblocks >> 3;
    const int id = blockIdx.x;
    const int swz = (id & 7) * chunk + (id >> 3);   // XCD-bijective swizzle
    const int qt   = swz & 63;
    const int rest = swz >> 6;
    const int sp = rest % nsplit;
    const int b  = rest / nsplit;
    const int q0 = qt * 64;
    const int w = t >> 6, lane = t & 63;
    const int lg = lane >> 4, lr = lane & 15;
    const int kvlen  = S_ / nsplit;
    const int iters  = kvlen >> 6;
    const int kvbase = sp * kvlen;

    // Q fragments hoisted to registers (read once)
    half8 qf[4];
    {
        const _Float16* qp = qh + (size_t)(b * S_ + q0 + w * 16 + lr) * H_ + 8 * lg;
        #pragma unroll
        for (int kk = 0; kk < 4; ++kk) qf[kk] = *(const half8*)(qp + kk * 32);
    }

    float m_[4], l_[4];
    f32x4 acc[8];
    #pragma unroll
    for (int r = 0; r < 4; ++r) { m_[r] = -1e30f; l_[r] = 0.f; }
    #pragma unroll
    for (int i = 0; i < 8; ++i) acc[i] = f32x4{0.f, 0.f, 0.f, 0.f};

    const int krow = t >> 2, kc = (t & 3) * 32;
    const int vrow = t >> 1, vc = (t & 1) * 32;

    for (int it = 0; it < iters; ++it) {
        const int kv0 = kvbase + it * 64;
        {   // stage K tile [64][128]
            const uint4* src = (const uint4*)(kh + (size_t)(b * S_ + kv0 + krow) * H_ + kc);
            #pragma unroll
            for (int i = 0; i < 4; ++i) *(uint4*)&Ks[krow][kc + 8 * i] = src[i];
        }
        {   // stage V^T tile [128][64]
            const uint4* src = (const uint4*)(vt + (size_t)b * H_ * S_ + (size_t)vrow * S_ + kv0 + vc);
            #pragma unroll
            for (int i = 0; i < 4; ++i) *(uint4*)&Vs[vrow][vc + 8 * i] = src[i];
        }
        if (t < 64) ms[t] = mask[b * S_ + kv0 + t];
        __syncthreads();

        // S = Q K^T (scale pre-applied to q)
        f32x4 sf[4];
        #pragma unroll
        for (int i = 0; i < 4; ++i) sf[i] = f32x4{0.f, 0.f, 0.f, 0.f};
        #pragma unroll
        for (int kk = 0; kk < 4; ++kk) {
            #pragma unroll
            for (int ni = 0; ni < 4; ++ni) {
                half8 kb = *(const half8*)&Ks[ni * 16 + lr][kk * 32 + 8 * lg];
                sf[ni] = __builtin_amdgcn_mfma_f32_16x16x32_f16(qf[kk], kb, sf[ni], 0, 0, 0);
            }
        }
        // padding mask (reference: where(mask==0, -1e9))
        #pragma unroll
        for (int ni = 0; ni < 4; ++ni) {
            if (ms[ni * 16 + lr] == 0) {
                #pragma unroll
                for (int r = 0; r < 4; ++r) sf[ni][r] = -1e9f;
            }
        }
        // online softmax: reduce across the 16-lane column group
        float rmax[4];
        #pragma unroll
        for (int r = 0; r < 4; ++r)
            rmax[r] = fmaxf(fmaxf(sf[0][r], sf[1][r]), fmaxf(sf[2][r], sf[3][r]));
        #pragma unroll
        for (int off = 1; off < 16; off <<= 1) {
            #pragma unroll
            for (int r = 0; r < 4; ++r)
                rmax[r] = fmaxf(rmax[r], __shfl_xor(rmax[r], off));
        }
        float sc[4], rsum[4];
        #pragma unroll
        for (int r = 0; r < 4; ++r) {
            float mn = fmaxf(m_[r], rmax[r]);
            sc[r] = expf(m_[r] - mn);
            m_[r] = mn;
            rsum[r] = 0.f;
        }
        #pragma unroll
        for (int ni = 0; ni < 4; ++ni) {
            #pragma unroll
            for (int r = 0; r < 4; ++r) {
                float p = expf(sf[ni][r] - m_[r]);
                sf[ni][r] = p;
                rsum[r] += p;
            }
        }
        #pragma unroll
        for (int off = 1; off < 16; off <<= 1) {
            #pragma unroll
            for (int r = 0; r < 4; ++r)
                rsum[r] += __shfl_xor(rsum[r], off);
        }
        #pragma unroll
        for (int r = 0; r < 4; ++r) l_[r] = l_[r] * sc[r] + rsum[r];
        #pragma unroll
        for (int ni = 0; ni < 8; ++ni) {
            #pragma unroll
            for (int r = 0; r < 4; ++r) acc[ni][r] *= sc[r];
        }
        // P -> per-wave LDS (C layout) then re-read as A fragments
        #pragma unroll
        for (int ni = 0; ni < 4; ++ni) {
            #pragma unroll
            for (int r = 0; r < 4; ++r)
                Ps[w][lg * 4 + r][ni * 16 + lr] = (_Float16)sf[ni][r];
        }
        // O += P V
        #pragma unroll
        for (int kk = 0; kk < 2; ++kk) {
            half8 pa = *(const half8*)&Ps[w][lr][kk * 32 + 8 * lg];
            #pragma unroll
            for (int ni = 0; ni < 8; ++ni) {
                half8 vb = *(const half8*)&Vs[ni * 16 + lr][kk * 32 + 8 * lg];
                acc[ni] = __builtin_amdgcn_mfma_f32_16x16x32_f16(pa, vb, acc[ni], 0, 0, 0);
            }
        }
        __syncthreads();
    }

    // store unnormalized partials
    const int rowb = b * S_ + q0 + w * 16 + lg * 4;   // global row id
    #pragma unroll
    for (int ni = 0; ni < 8; ++ni) {
        const int col = ni * 16 + lr;
        #pragma unroll
        for (int r = 0; r < 4; ++r)
            pout[(size_t)(sp * M_ + rowb + r) * H_ + col] = acc[ni][r];
    }
    if (lr == 0) {
        #pragma unroll
        for (int r = 0; r < 4; ++r) {
            pm[sp * M_ + rowb + r] = m_[r];
            pl[sp * M_ + rowb + r] = l_[r];
        }
    }
}

// ---------------------------------------------------------------------------
// Kernel 3: combine KV-split partials and normalize.
// ---------------------------------------------------------------------------
__global__ __launch_bounds__(256) void combine_kernel(
    const float* __restrict__ pout, const float* __restrict__ pm,
    const float* __restrict__ pl, float* __restrict__ out, const int nsplit)
{
    const int idx = blockIdx.x * 256 + threadIdx.x;
    const int row = idx >> 7;          // global row
    const int h   = idx & (H_ - 1);
    float M = -1e30f;
    for (int sp = 0; sp < nsplit; ++sp) M = fmaxf(M, pm[sp * M_ + row]);
    float Z = 0.f, o = 0.f;
    for (int sp = 0; sp < nsplit; ++sp) {
        const float wgt = expf(pm[sp * M_ + row] - M);
        Z += wgt * pl[sp * M_ + row];
        o += wgt * pout[(size_t)(sp * M_ + row) * H_ + h];
    }
    out[idx] = o / Z;
}

// ---------------------------------------------------------------------------
extern "C" void kernel_launch(void* const* d_in, const int* in_sizes, int n_in,
                              void* d_out, int out_size, void* d_ws, size_t ws_size,
                              hipStream_t stream)
{
    (void)in_sizes; (void)n_in; (void)out_size;
    // setup_inputs order: inputs, Wk, bk, Wq, bq, Wv, bv, padding_mask
    const float* x  = (const float*)d_in[0];
    const float* Wk = (const float*)d_in[1];
    const float* bk = (const float*)d_in[2];
    const float* Wq = (const float*)d_in[3];
    const float* bq = (const float*)d_in[4];
    const float* Wv = (const float*)d_in[5];
    const float* bv = (const float*)d_in[6];
    const int* mask = (const int*)d_in[7];

    char* ws = (char*)d_ws;
    const size_t qkvBytes = (size_t)M_ * H_ * sizeof(_Float16);   // 4 MB each
    _Float16* qh = (_Float16*)ws;
    _Float16* kh = (_Float16*)(ws + qkvBytes);
    _Float16* vt = (_Float16*)(ws + 2 * qkvBytes);                // [B][H][S]
    char* rest = ws + 3 * qkvBytes;

    // KV-split sized to workspace: prefer 4 (occupancy), degrade if ws is small
    int nsplit = 4;
    const size_t perSplit = (size_t)M_ * H_ * 4 + 2 * (size_t)M_ * 4;
    while (nsplit > 1 && 3 * qkvBytes + (size_t)nsplit * perSplit > ws_size) nsplit >>= 1;

    float* pout = (float*)rest;
    float* pm   = (float*)(rest + (size_t)nsplit * M_ * H_ * 4);
    float* pl   = pm + (size_t)nsplit * M_;

    proj_kernel<<<dim3(M_ / 64, 3), 256, 0, stream>>>(x, Wq, bq, Wk, bk, Wv, bv, qh, kh, vt);
    attn_kernel<<<dim3(256 * nsplit), 256, 0, stream>>>(qh, kh, vt, mask, pout, pm, pl, nsplit);
    combine_kernel<<<dim3(M_ * H_ / 256), 256, 0, stream>>>(pout, pm, pl, (float*)d_out, nsplit);
}